// Round 1
// baseline (458.436 us; speedup 1.0000x reference)
//
#include <hip/hip_runtime.h>
#include <stdint.h>

#define B_    8
#define N_    2048
#define INF_  128
#define H_    4
#define OUTF_ 32
#define BH_   (B_ * H_)
#define ALPHA_ 0.2f

// ---------------- workspace layout (bytes) ----------------
// hmat   : [BH][N][32] f32   @ 0          (8 MB)
// bits   : [N][N/64]  u64    @ 8388608    (512 KB)
// Aarr   : [BH][N] f32       @ 8912896    (e^{s})
// Barr   : [BH][N] f32                    (e^{alpha*s})
// nsarr  : [BH][N] f32                    (-s)
// darr   : [BH][N] f32                    (d)
// uarr   : [BH][N] f32                    (e^{d})
// varr   : [BH][N] f32                    (e^{alpha*d})
// total ~10.25 MB

// ---------------- K0: pack adjacency into 64-bit masks ----------------
__global__ __launch_bounds__(256) void k_pack_adj(const int* __restrict__ adj,
                                                  unsigned long long* __restrict__ bits) {
  const int i = blockIdx.x;
  const int t = threadIdx.x;
  const int* row = adj + (size_t)i * N_;
#pragma unroll
  for (int it = 0; it < N_ / 256; ++it) {
    const int j = it * 256 + t;
    const unsigned long long m = __ballot(row[j] != 0);
    if ((t & 63) == 0) bits[(size_t)i * (N_ / 64) + it * 4 + (t >> 6)] = m;
  }
}

// ---------------- K1: h = x@W, plus per-node attention arrays ----------------
__global__ __launch_bounds__(256) void k_feat(const float* __restrict__ x,
                                              const float* __restrict__ W,
                                              const float* __restrict__ asrc,
                                              const float* __restrict__ adst,
                                              float* __restrict__ hout,
                                              float* __restrict__ Aarr,
                                              float* __restrict__ Barr,
                                              float* __restrict__ nsarr,
                                              float* __restrict__ darr,
                                              float* __restrict__ uarr,
                                              float* __restrict__ varr) {
  __shared__ float Ws[INF_][OUTF_];   // 16 KB
  __shared__ float xs[8][INF_];       // 4 KB
  __shared__ float as_s[OUTF_], ad_s[OUTF_];

  const int t = threadIdx.x;
  const int blk = blockIdx.x;       // bh*8 + chunk
  const int bh = blk >> 3, chunk = blk & 7;
  const int b = bh >> 2, hh = bh & 3;

  for (int idx = t; idx < INF_ * OUTF_; idx += 256)
    Ws[idx / OUTF_][idx % OUTF_] = W[hh * INF_ * OUTF_ + idx];
  if (t < OUTF_) { as_s[t] = asrc[hh * OUTF_ + t]; ad_s[t] = adst[hh * OUTF_ + t]; }

  const int col = t & 31, rsub = t >> 5;   // 8 rows x 32 cols per iteration
  const int xr = t >> 5, xq = t & 31;      // x staging map

  for (int it = 0; it < 32; ++it) {
    const int i0 = chunk * 256 + it * 8;
    __syncthreads();  // protect xs from previous iteration's readers
    ((float4*)&xs[xr][0])[xq] =
        ((const float4*)(x + ((size_t)b * N_ + i0 + xr) * INF_))[xq];
    __syncthreads();

    float acc = 0.f;
#pragma unroll
    for (int k = 0; k < INF_; k += 4) {
      const float4 xv = *(const float4*)&xs[rsub][k];
      acc += xv.x * Ws[k + 0][col];
      acc += xv.y * Ws[k + 1][col];
      acc += xv.z * Ws[k + 2][col];
      acc += xv.w * Ws[k + 3][col];
    }
    hout[((size_t)bh * N_ + i0 + rsub) * OUTF_ + col] = acc;

    float es = acc * as_s[col];
    float ed = acc * ad_s[col];
#pragma unroll
    for (int m = 16; m >= 1; m >>= 1) {
      es += __shfl_xor(es, m, 32);
      ed += __shfl_xor(ed, m, 32);
    }
    if (col == 0) {
      const int ri = bh * N_ + i0 + rsub;
      Aarr[ri]  = expf(es);
      Barr[ri]  = expf(ALPHA_ * es);
      nsarr[ri] = -es;
      darr[ri]  = ed;
      uarr[ri]  = expf(ed);
      varr[ri]  = expf(ALPHA_ * ed);
    }
  }
}

// ---------------- K3: fused masked-softmax @ h (the heavy kernel) ----------------
#define R_  128   // rows per block
#define TJ_ 64    // j-tile

__global__ __launch_bounds__(256) void k_attn(const float* __restrict__ hmat,
                                              const unsigned long long* __restrict__ bits,
                                              const float* __restrict__ Aarr,
                                              const float* __restrict__ Barr,
                                              const float* __restrict__ nsarr,
                                              const float* __restrict__ darr,
                                              const float* __restrict__ uarr,
                                              const float* __restrict__ varr,
                                              float* __restrict__ out) {
  __shared__ float w_s[R_ * 65];           // +1 pad: stride 65 floats, 33280 B
  __shared__ float h_s[TJ_ * OUTF_];       // 8 KB
  __shared__ float ns_l[R_], A_l[R_], B_l[R_];

  const int t = threadIdx.x;
  const int blk = blockIdx.x;              // bh*16 + tile
  const int bh = blk >> 4, itile = blk & 15;
  const int i0 = itile * R_;
  const int b = bh >> 2, hh = bh & 3;

  const float* hg = hmat + (size_t)bh * N_ * OUTF_;
  const float* dg = darr + (size_t)bh * N_;
  const float* ug = uarr + (size_t)bh * N_;
  const float* vg = varr + (size_t)bh * N_;

  if (t < R_) {
    const int ri = bh * N_ + i0 + t;
    ns_l[t] = nsarr[ri];
    A_l[t]  = Aarr[ri];
    B_l[t]  = Barr[ri];
  }

  float4 acc[4];
  float zacc[4];
#pragma unroll
  for (int r = 0; r < 4; ++r) {
    acc[r] = make_float4(0.f, 0.f, 0.f, 0.f);
    zacc[r] = 0.f;
  }

  const int jj = t & 63, rsub = t >> 6;    // w-staging map (wave-uniform row)
  const int tx = t & 7, ty = t >> 3;       // compute map: rows 4*ty.., cols 4*tx..

  __syncthreads();

  for (int jt = 0; jt < N_ / TJ_; ++jt) {
    const int j0 = jt * TJ_;

    // stage h tile (64 x 32 f32 = 512 float4)
    {
      const float4* hg4 = (const float4*)(hg + (size_t)j0 * OUTF_);
      float4* hs4 = (float4*)h_s;
      hs4[t]       = hg4[t];
      hs4[t + 256] = hg4[t + 256];
    }

    // stage masked softmax weights w[row][jj]
    const float dj = dg[j0 + jj];
    const float uj = ug[j0 + jj];
    const float vj = vg[j0 + jj];
#pragma unroll 4
    for (int k = 0; k < R_ / 4; ++k) {
      const int row = rsub + 4 * k;                       // wave-uniform
      const unsigned long long wrd = bits[(size_t)(i0 + row) * (N_ / 64) + jt];
      const bool bit = (wrd >> jj) & 1ULL;
      const float wgt = bit ? ((dj > ns_l[row]) ? A_l[row] * uj : B_l[row] * vj) : 0.f;
      w_s[row * 65 + jj] = wgt;
    }
    __syncthreads();

    // C[128x32] += w[128x64] * h[64x32], 4x4 per thread
    const float4* hs4 = (const float4*)h_s;
#pragma unroll 2
    for (int q = 0; q < TJ_; q += 4) {
      const float4 h0 = hs4[(q + 0) * 8 + tx];
      const float4 h1 = hs4[(q + 1) * 8 + tx];
      const float4 h2 = hs4[(q + 2) * 8 + tx];
      const float4 h3 = hs4[(q + 3) * 8 + tx];
#pragma unroll
      for (int r = 0; r < 4; ++r) {
        const float* wp = &w_s[(ty * 4 + r) * 65 + q];
        const float w0 = wp[0], w1 = wp[1], w2 = wp[2], w3 = wp[3];
        acc[r].x += w0 * h0.x + w1 * h1.x + w2 * h2.x + w3 * h3.x;
        acc[r].y += w0 * h0.y + w1 * h1.y + w2 * h2.y + w3 * h3.y;
        acc[r].z += w0 * h0.z + w1 * h1.z + w2 * h2.z + w3 * h3.z;
        acc[r].w += w0 * h0.w + w1 * h1.w + w2 * h2.w + w3 * h3.w;
        zacc[r] += (w0 + w1) + (w2 + w3);
      }
    }
    __syncthreads();
  }

  // epilogue: out[b][i][hh*32 + c] = acc / Z
#pragma unroll
  for (int r = 0; r < 4; ++r) {
    const int i = i0 + ty * 4 + r;
    const float inv = 1.0f / zacc[r];
    float4 o;
    o.x = acc[r].x * inv;
    o.y = acc[r].y * inv;
    o.z = acc[r].z * inv;
    o.w = acc[r].w * inv;
    *(float4*)(out + (((size_t)b * N_ + i) * H_ + hh) * OUTF_ + tx * 4) = o;
  }
}

extern "C" void kernel_launch(void* const* d_in, const int* in_sizes, int n_in,
                              void* d_out, int out_size, void* d_ws, size_t ws_size,
                              hipStream_t stream) {
  const float* x    = (const float*)d_in[0];
  const int*   adj  = (const int*)d_in[1];
  const float* W    = (const float*)d_in[2];
  const float* asrc = (const float*)d_in[3];
  const float* adst = (const float*)d_in[4];
  float* out = (float*)d_out;

  char* ws = (char*)d_ws;
  float* hmat = (float*)ws;                                         // 8 MB
  unsigned long long* bits = (unsigned long long*)(ws + 8388608);   // 512 KB
  float* Aarr  = (float*)(ws + 8912896);
  float* Barr  = Aarr  + BH_ * N_;
  float* nsarr = Barr  + BH_ * N_;
  float* darr  = nsarr + BH_ * N_;
  float* uarr  = darr  + BH_ * N_;
  float* varr  = uarr  + BH_ * N_;

  hipLaunchKernelGGL(k_pack_adj, dim3(N_), dim3(256), 0, stream, adj, bits);
  hipLaunchKernelGGL(k_feat, dim3(BH_ * 8), dim3(256), 0, stream,
                     x, W, asrc, adst, hmat, Aarr, Barr, nsarr, darr, uarr, varr);
  hipLaunchKernelGGL(k_attn, dim3(BH_ * (N_ / R_)), dim3(256), 0, stream,
                     hmat, bits, Aarr, Barr, nsarr, darr, uarr, varr, out);
}

// Round 6
// 265.700 us; speedup vs baseline: 1.7254x; 1.7254x over previous
//
#include <hip/hip_runtime.h>
#include <stdint.h>

#define B_    8
#define N_    2048
#define INF_  128
#define H_    4
#define OUTF_ 32
#define BH_   (B_*H_)
#define ALPHA_ 0.2f

typedef __attribute__((ext_vector_type(8))) short bf16x8;
typedef __attribute__((ext_vector_type(4))) short bf16x4;
typedef __attribute__((ext_vector_type(4))) float f32x4;

static __device__ __forceinline__ short bf16_rne(float f) {
  uint32_t u = __float_as_uint(f);
  u += 0x7fffu + ((u >> 16) & 1u);
  return (short)(u >> 16);
}
// split f into bf16 hi (truncate) + bf16 lo (rne of residual): hi+lo ~ f to 2^-17
// macro (not ref-taking fn): vector elements can't bind to short&
#define BF16_SPLIT(f, dsthi, dstlo) {                         \
    const float f_ = (f);                                     \
    const uint32_t uh_ = __float_as_uint(f_) & 0xffff0000u;   \
    (dsthi) = (short)(uh_ >> 16);                             \
    (dstlo) = bf16_rne(f_ - __uint_as_float(uh_)); }

// ---------------- workspace layout (bytes) ----------------
// hThi  : bf16 [BH][32][N]   @ 0         (4 MB)
// hTlo  : bf16 [BH][32][N]   @ 4194304   (4 MB)
// bits  : u64  [N][N/64]     @ 8388608   (512 KB)
// Aarr..varr : f32 [BH][N] x6 @ 8912896  (1.5 MB)
// WThi  : bf16 [H][32][128]  @ 10485760  (32 KB)
// WTlo  : bf16 [H][32][128]  @ 10518528  (32 KB)

// ---------------- K0a: transpose W to split-bf16 WT[h][c][k] ----------------
__global__ void k_wt(const float* __restrict__ W, short* __restrict__ WThi,
                     short* __restrict__ WTlo) {
  const int h = blockIdx.x, k = threadIdx.x;  // 4 blocks x 128 threads
#pragma unroll
  for (int c = 0; c < OUTF_; ++c) {
    short hi, lo;
    BF16_SPLIT(W[(h * INF_ + k) * OUTF_ + c], hi, lo);
    WThi[(h * OUTF_ + c) * INF_ + k] = hi;
    WTlo[(h * OUTF_ + c) * INF_ + k] = lo;
  }
}

// ---------------- K0b: pack adjacency into 64-bit masks ----------------
__global__ __launch_bounds__(256) void k_pack_adj(const int* __restrict__ adj,
                                                  unsigned long long* __restrict__ bits) {
  const int i = blockIdx.x;
  const int t = threadIdx.x;
  const int* row = adj + (size_t)i * N_;
#pragma unroll
  for (int it = 0; it < N_ / 256; ++it) {
    const int j = it * 256 + t;
    const unsigned long long m = __ballot(row[j] != 0);
    if ((t & 63) == 0) bits[(size_t)i * (N_ / 64) + it * 4 + (t >> 6)] = m;
  }
}

// ---------------- K1: h = x@W via split-bf16 MFMA (fp32-accurate) ----------------
__global__ __launch_bounds__(256) void k_feat(const float* __restrict__ x,
    const short* __restrict__ WThi, const short* __restrict__ WTlo,
    const float* __restrict__ asrc, const float* __restrict__ adst,
    short* __restrict__ hThi, short* __restrict__ hTlo,
    float* __restrict__ Aarr, float* __restrict__ Barr, float* __restrict__ nsarr,
    float* __restrict__ darr, float* __restrict__ uarr, float* __restrict__ varr)
{
  const int t = threadIdx.x, lane = t & 63, wv = t >> 6;
  const int blk = blockIdx.x, bh = blk >> 5, itile = blk & 31;
  const int b = bh >> 2, hh = bh & 3;
  const int i0 = itile * 64 + wv * 16;
  const int cl = lane & 15, g = lane >> 4;

  const float* xr   = x + ((size_t)b * N_ + i0 + cl) * INF_ + g * 8;
  const size_t wo0 = (size_t)(hh * OUTF_ + cl) * INF_ + g * 8;
  const size_t wo1 = (size_t)(hh * OUTF_ + 16 + cl) * INF_ + g * 8;

  f32x4 acc0 = {0.f, 0.f, 0.f, 0.f}, acc1 = {0.f, 0.f, 0.f, 0.f};
#pragma unroll
  for (int kt = 0; kt < 4; ++kt) {
    const int kb = kt * 32;
    const f32x4 xa = *(const f32x4*)(xr + kb);
    const f32x4 xb = *(const f32x4*)(xr + kb + 4);
    bf16x8 ah, al;
    BF16_SPLIT(xa[0], ah[0], al[0]); BF16_SPLIT(xa[1], ah[1], al[1]);
    BF16_SPLIT(xa[2], ah[2], al[2]); BF16_SPLIT(xa[3], ah[3], al[3]);
    BF16_SPLIT(xb[0], ah[4], al[4]); BF16_SPLIT(xb[1], ah[5], al[5]);
    BF16_SPLIT(xb[2], ah[6], al[6]); BF16_SPLIT(xb[3], ah[7], al[7]);
    const bf16x8 b0h = *(const bf16x8*)(WThi + wo0 + kb);
    const bf16x8 b0l = *(const bf16x8*)(WTlo + wo0 + kb);
    const bf16x8 b1h = *(const bf16x8*)(WThi + wo1 + kb);
    const bf16x8 b1l = *(const bf16x8*)(WTlo + wo1 + kb);
    // (ah+al)(bh+bl) ~= ah*bh + al*bh + ah*bl  (al*bl ~ 2^-34, dropped)
    acc0 = __builtin_amdgcn_mfma_f32_16x16x32_bf16(ah, b0h, acc0, 0, 0, 0);
    acc0 = __builtin_amdgcn_mfma_f32_16x16x32_bf16(al, b0h, acc0, 0, 0, 0);
    acc0 = __builtin_amdgcn_mfma_f32_16x16x32_bf16(ah, b0l, acc0, 0, 0, 0);
    acc1 = __builtin_amdgcn_mfma_f32_16x16x32_bf16(ah, b1h, acc1, 0, 0, 0);
    acc1 = __builtin_amdgcn_mfma_f32_16x16x32_bf16(al, b1h, acc1, 0, 0, 0);
    acc1 = __builtin_amdgcn_mfma_f32_16x16x32_bf16(ah, b1l, acc1, 0, 0, 0);
  }

  // hT[bh][c][j]: C-frag rows (l>>4)*4+q are consecutive j -> 8B packed stores
  bf16x4 h0h, h0l, h1h, h1l;
  BF16_SPLIT(acc0[0], h0h[0], h0l[0]); BF16_SPLIT(acc0[1], h0h[1], h0l[1]);
  BF16_SPLIT(acc0[2], h0h[2], h0l[2]); BF16_SPLIT(acc0[3], h0h[3], h0l[3]);
  BF16_SPLIT(acc1[0], h1h[0], h1l[0]); BF16_SPLIT(acc1[1], h1h[1], h1l[1]);
  BF16_SPLIT(acc1[2], h1h[2], h1l[2]); BF16_SPLIT(acc1[3], h1h[3], h1l[3]);
  const size_t jw = (size_t)i0 + g * 4;
  const size_t c0 = ((size_t)bh * OUTF_ + cl) * N_ + jw;
  const size_t c1 = ((size_t)bh * OUTF_ + 16 + cl) * N_ + jw;
  *(bf16x4*)(hThi + c0) = h0h;
  *(bf16x4*)(hTlo + c0) = h0l;
  *(bf16x4*)(hThi + c1) = h1h;
  *(bf16x4*)(hTlo + c1) = h1l;

  // s_i = h_i . a_src, d_i = h_i . a_dst  (reduce over col dim = 16 lanes)
  const float as0 = asrc[hh * OUTF_ + cl], as1 = asrc[hh * OUTF_ + 16 + cl];
  const float ad0 = adst[hh * OUTF_ + cl], ad1 = adst[hh * OUTF_ + 16 + cl];
  float es0 = acc0[0] * as0 + acc1[0] * as1;
  float es1 = acc0[1] * as0 + acc1[1] * as1;
  float es2 = acc0[2] * as0 + acc1[2] * as1;
  float es3 = acc0[3] * as0 + acc1[3] * as1;
  float ed0 = acc0[0] * ad0 + acc1[0] * ad1;
  float ed1 = acc0[1] * ad0 + acc1[1] * ad1;
  float ed2 = acc0[2] * ad0 + acc1[2] * ad1;
  float ed3 = acc0[3] * ad0 + acc1[3] * ad1;
#pragma unroll
  for (int m = 1; m <= 8; m <<= 1) {
    es0 += __shfl_xor(es0, m); es1 += __shfl_xor(es1, m);
    es2 += __shfl_xor(es2, m); es3 += __shfl_xor(es3, m);
    ed0 += __shfl_xor(ed0, m); ed1 += __shfl_xor(ed1, m);
    ed2 += __shfl_xor(ed2, m); ed3 += __shfl_xor(ed3, m);
  }
  if (cl < 4) {
    const float s  = cl == 0 ? es0 : cl == 1 ? es1 : cl == 2 ? es2 : es3;
    const float dd = cl == 0 ? ed0 : cl == 1 ? ed1 : cl == 2 ? ed2 : ed3;
    const size_t ri = (size_t)bh * N_ + i0 + g * 4 + cl;
    Aarr[ri]  = expf(s);
    Barr[ri]  = expf(ALPHA_ * s);
    nsarr[ri] = -s;
    darr[ri]  = dd;
    uarr[ri]  = expf(dd);
    varr[ri]  = expf(ALPHA_ * dd);
  }
}

// ---------------- K3: fused masked-softmax @ h via MFMA, LDS-free ----------------
__global__ __launch_bounds__(256) void k_attn(const short* __restrict__ hThi,
    const short* __restrict__ hTlo, const uint32_t* __restrict__ bits32,
    const float* __restrict__ Aarr, const float* __restrict__ Barr,
    const float* __restrict__ nsarr, const float* __restrict__ darr,
    const float* __restrict__ uarr, const float* __restrict__ varr,
    float* __restrict__ out)
{
  const int t = threadIdx.x, lane = t & 63, wv = t >> 6;
  const int blk = blockIdx.x, bh = blk >> 5, itile = blk & 31;
  const int b = bh >> 2, hh = bh & 3;
  const int i0 = itile * 64 + wv * 16;   // 16 rows per wave
  const int cl = lane & 15, g = lane >> 4;
  const int jb = g * 8;

  const size_t rbase = (size_t)bh * N_;
  const float Ai  = Aarr[rbase + i0 + cl];
  const float Bi  = Barr[rbase + i0 + cl];
  const float nsi = nsarr[rbase + i0 + cl];
  const float* dg = darr + rbase;
  const float* ug = uarr + rbase;
  const float* vg = varr + rbase;
  const uint32_t* brow = bits32 + (size_t)(i0 + cl) * (N_ / 32);
  const size_t hc0 = ((size_t)bh * OUTF_ + cl) * N_;
  const size_t hc1 = ((size_t)bh * OUTF_ + 16 + cl) * N_;

  f32x4 acc0 = {0.f, 0.f, 0.f, 0.f}, acc1 = {0.f, 0.f, 0.f, 0.f};
  float z = 0.f;

#define WGEN(E, DE, UE, VE) {                                   \
    const bool c_ = (DE) > nsi;                                 \
    float w_ = (c_ ? Ai : Bi) * (c_ ? (UE) : (VE));             \
    w_ = ((wsh >> (E)) & 1u) ? w_ : 0.f;                        \
    const uint32_t hi_ = __float_as_uint(w_) & 0xffff0000u;     \
    whi[E] = (short)(hi_ >> 16);                                \
    wlo[E] = (short)(__float_as_uint(w_ - __uint_as_float(hi_)) >> 16); \
    z += w_; }

#pragma unroll 2
  for (int jt = 0; jt < N_ / 32; ++jt) {
    const int j0 = jt * 32 + jb;
    const f32x4 d0 = *(const f32x4*)(dg + j0);
    const f32x4 d1 = *(const f32x4*)(dg + j0 + 4);
    const f32x4 u0 = *(const f32x4*)(ug + j0);
    const f32x4 u1 = *(const f32x4*)(ug + j0 + 4);
    const f32x4 v0 = *(const f32x4*)(vg + j0);
    const f32x4 v1 = *(const f32x4*)(vg + j0 + 4);
    const bf16x8 h0h = *(const bf16x8*)(hThi + hc0 + j0);
    const bf16x8 h0l = *(const bf16x8*)(hTlo + hc0 + j0);
    const bf16x8 h1h = *(const bf16x8*)(hThi + hc1 + j0);
    const bf16x8 h1l = *(const bf16x8*)(hTlo + hc1 + j0);
    const uint32_t wsh = brow[jt] >> jb;

    bf16x8 whi, wlo;
    WGEN(0, d0[0], u0[0], v0[0])
    WGEN(1, d0[1], u0[1], v0[1])
    WGEN(2, d0[2], u0[2], v0[2])
    WGEN(3, d0[3], u0[3], v0[3])
    WGEN(4, d1[0], u1[0], v1[0])
    WGEN(5, d1[1], u1[1], v1[1])
    WGEN(6, d1[2], u1[2], v1[2])
    WGEN(7, d1[3], u1[3], v1[3])

    // w*h ~= whi*hhi + wlo*hhi + whi*hlo  (fp32-equivalent numerator)
    acc0 = __builtin_amdgcn_mfma_f32_16x16x32_bf16(whi, h0h, acc0, 0, 0, 0);
    acc0 = __builtin_amdgcn_mfma_f32_16x16x32_bf16(wlo, h0h, acc0, 0, 0, 0);
    acc0 = __builtin_amdgcn_mfma_f32_16x16x32_bf16(whi, h0l, acc0, 0, 0, 0);
    acc1 = __builtin_amdgcn_mfma_f32_16x16x32_bf16(whi, h1h, acc1, 0, 0, 0);
    acc1 = __builtin_amdgcn_mfma_f32_16x16x32_bf16(wlo, h1h, acc1, 0, 0, 0);
    acc1 = __builtin_amdgcn_mfma_f32_16x16x32_bf16(whi, h1l, acc1, 0, 0, 0);
  }
#undef WGEN

  // Z per row (row = cl): combine the 4 j-groups
  z += __shfl_xor(z, 16);
  z += __shfl_xor(z, 32);

  // epilogue: C-frag row = g*4+q, col = cl; fetch that row's Z via shfl
  float* op = out + ((size_t)b * N_ + i0) * (H_ * OUTF_) + hh * OUTF_;
#pragma unroll
  for (int q = 0; q < 4; ++q) {
    const float zr = __shfl(z, g * 4 + q);
    const float inv = 1.0f / zr;
    op[(size_t)(g * 4 + q) * (H_ * OUTF_) + cl]      = acc0[q] * inv;
    op[(size_t)(g * 4 + q) * (H_ * OUTF_) + 16 + cl] = acc1[q] * inv;
  }
}

extern "C" void kernel_launch(void* const* d_in, const int* in_sizes, int n_in,
                              void* d_out, int out_size, void* d_ws, size_t ws_size,
                              hipStream_t stream) {
  const float* x    = (const float*)d_in[0];
  const int*   adj  = (const int*)d_in[1];
  const float* W    = (const float*)d_in[2];
  const float* asrc = (const float*)d_in[3];
  const float* adst = (const float*)d_in[4];
  float* out = (float*)d_out;

  char* ws = (char*)d_ws;
  short* hThi = (short*)ws;                                         // 4 MB
  short* hTlo = (short*)(ws + 4194304);                             // 4 MB
  unsigned long long* bits = (unsigned long long*)(ws + 8388608);   // 512 KB
  float* Aarr  = (float*)(ws + 8912896);
  float* Barr  = Aarr  + BH_ * N_;
  float* nsarr = Barr  + BH_ * N_;
  float* darr  = nsarr + BH_ * N_;
  float* uarr  = darr  + BH_ * N_;
  float* varr  = uarr  + BH_ * N_;
  short* WThi  = (short*)(ws + 10485760);                           // 32 KB
  short* WTlo  = (short*)(ws + 10518528);                           // 32 KB

  hipLaunchKernelGGL(k_wt, dim3(H_), dim3(INF_), 0, stream, W, WThi, WTlo);
  hipLaunchKernelGGL(k_pack_adj, dim3(N_), dim3(256), 0, stream, adj, bits);
  hipLaunchKernelGGL(k_feat, dim3(BH_ * 32), dim3(256), 0, stream,
                     x, WThi, WTlo, asrc, adst, hThi, hTlo,
                     Aarr, Barr, nsarr, darr, uarr, varr);
  hipLaunchKernelGGL(k_attn, dim3(BH_ * 32), dim3(256), 0, stream,
                     hThi, hTlo, (const uint32_t*)bits,
                     Aarr, Barr, nsarr, darr, uarr, varr, out);
}